// Round 5
// baseline (24.072 us; speedup 1.0000x reference)
//
#include <hip/hip_runtime.h>

typedef float v2f __attribute__((ext_vector_type(2)));

// Structural constants (mirror reference)
#define NPOSE 64
#define NROT  128
#define NATOM 8
#define EPS   1e-2f

#define TS    16                 // rotamer tile size
#define NTILE (NROT / TS)        // 8 tiles per axis
#define NPAIR (NTILE * (NTILE + 1) / 2)   // 36 tile pairs (ti <= tj)
#define CSTR  28                 // coord LDS row stride: 24 + 4 pad, 16B-aligned rows
#define SSTR  17                 // result tile row stride (16 + 1 pad)

// One wave per block: 2304 waves total = 9 waves/CU -> fully resident, no convoying.
__global__ __launch_bounds__(64, 4) void rot_score_kernel(
    const float* __restrict__ coords,
    float* __restrict__ out)
{
    __shared__ float ldsI[TS * CSTR];
    __shared__ float ldsJ[TS * CSTR];
    __shared__ float res0[TS * SSTR];
    __shared__ float res1[TS * SSTR];

    const int bid = blockIdx.x;
    const int p   = bid / NPAIR;
    int t = bid - p * NPAIR;
    int ti = 0;
    while (t >= NTILE - ti) { t -= NTILE - ti; ++ti; }   // unrank upper triangle
    const int tj = ti + t;

    const int lane = threadIdx.x;   // 0..63
    const float* src = coords + (size_t)p * (NROT * NATOM * 3);

    // Stage the two 16-rotamer coordinate sets (16 x 24 floats each), coalesced.
    for (int idx = lane; idx < 2 * TS * 24; idx += 64) {
        const int set = idx >= TS * 24;          // uniform per iteration
        const int loc = idx - set * (TS * 24);
        const int r   = loc / 24;
        const int k   = loc - r * 24;
        const float v = src[(set ? tj : ti) * (TS * 24) + loc];
        (set ? ldsJ : ldsI)[r * CSTR + k] = v;
    }
    __syncthreads();

    const int ty  = lane >> 2;    // tile row 0..15
    const int txg = lane & 3;     // owns 4 consecutive cols: txg*4 .. txg*4+3

    // i-rotamer atoms in registers (4-lane broadcast reads).
    float4 xi4[6];
    {
        const float4* rowI = (const float4*)&ldsI[ty * CSTR];
#pragma unroll
        for (int k = 0; k < 6; ++k) xi4[k] = rowI[k];
    }
    float* xi = (float*)xi4;

    float sqi[NATOM];
#pragma unroll
    for (int a = 0; a < NATOM; ++a)
        sqi[a] = fmaf(xi[a*3+2], xi[a*3+2], fmaf(xi[a*3+1], xi[a*3+1], xi[a*3+0]*xi[a*3+0]));
    // pre-scale xi by -2 so d2 = sqi + sqj + sum(xi2*xj) is a pure fma chain
#pragma unroll
    for (int k = 0; k < 24; ++k) xi[k] = xi[k] * -2.0f;

    const float SCH_S = -12102203.0f;   // -(2^23)/ln2  (Schraudolph exp)
    const float SCH_B = 1064866805.0f;  // bias

    float4 s0q, s1q;
    float* s0p = (float*)&s0q;
    float* s1p = (float*)&s1q;

#pragma unroll
    for (int jj = 0; jj < 4; ++jj) {
        const int tx = txg * 4 + jj;
        float4 xj4[6];
        {
            const float4* rowJ = (const float4*)&ldsJ[tx * CSTR];
#pragma unroll
            for (int k = 0; k < 6; ++k) xj4[k] = rowJ[k];
        }
        const float* xj = (const float*)xj4;

        v2f s0v = { 0.0f, 0.0f }, s1v = { 0.0f, 0.0f };
        const v2f veps = { EPS, EPS };

#pragma unroll
        for (int bp = 0; bp < 4; ++bp) {
            // pack j-atoms (2bp, 2bp+1)
            const v2f ax = { xj[bp*6 + 0], xj[bp*6 + 3] };
            const v2f ay = { xj[bp*6 + 1], xj[bp*6 + 4] };
            const v2f az = { xj[bp*6 + 2], xj[bp*6 + 5] };
            const v2f sj = __builtin_elementwise_fma(az, az,
                            __builtin_elementwise_fma(ay, ay, ax * ax));
#pragma unroll
            for (int a = 0; a < NATOM; ++a) {
                v2f t = sj + sqi[a];                                   // pk_add (splat)
                t = __builtin_elementwise_fma((v2f)(xi[a*3+0]), ax, t);
                t = __builtin_elementwise_fma((v2f)(xi[a*3+1]), ay, t);
                t = __builtin_elementwise_fma((v2f)(xi[a*3+2]), az, t); // t = d2 pair
                t = __builtin_elementwise_max(t, veps);
                const v2f rs = { __builtin_amdgcn_rsqf(t.x),
                                 __builtin_amdgcn_rsqf(t.y) };
                s0v = __builtin_elementwise_fma(rs, rs, s0v);          // += 1/d2
                const v2f dv = t * rs;                                 // sqrt(d2)
                const v2f st = __builtin_elementwise_fma(dv, (v2f)(SCH_S), (v2f)(SCH_B));
                v2f e;
                e.x = __int_as_float((int)st.x);                       // ~ exp(-d)
                e.y = __int_as_float((int)st.y);
                s1v += e;
            }
        }
        s0p[jj] = s0v.x + s0v.y;
        s1p[jj] = s1v.x + s1v.y;
    }

    // Stage results for the transposed mirror read.
#pragma unroll
    for (int k = 0; k < 4; ++k) {
        res0[ty * SSTR + txg * 4 + k] = s0p[k];
        res1[ty * SSTR + txg * 4 + k] = s1p[k];
    }

    const int nnz  = NPOSE * NROT * NROT;
    const int gi   = ti * TS + ty;
    const int col0 = tj * TS + txg * 4;
    const int n    = (p * NROT + gi) * NROT + col0;     // multiple of 4

    const float fp  = (float)p;
    const float ri  = (float)(p * NROT + gi);
    const float rj0 = (float)(p * NROT + col0);

    *(float4*)(out + (size_t)0 * nnz + n) = s0q;
    *(float4*)(out + (size_t)1 * nnz + n) = s1q;
    *(float4*)(out + (size_t)2 * nnz + n) = make_float4(fp, fp, fp, fp);
    *(float4*)(out + (size_t)3 * nnz + n) = make_float4(ri, ri, ri, ri);
    *(float4*)(out + (size_t)4 * nnz + n) = make_float4(rj0, rj0 + 1.0f, rj0 + 2.0f, rj0 + 3.0f);

    if (ti != tj) {              // block-uniform mirror
        __syncthreads();
        float4 m0q, m1q;
        float* m0p = (float*)&m0q;
        float* m1p = (float*)&m1q;
#pragma unroll
        for (int k = 0; k < 4; ++k) {
            m0p[k] = res0[(txg * 4 + k) * SSTR + ty];   // transposed read
            m1p[k] = res1[(txg * 4 + k) * SSTR + ty];
        }
        const int mi    = tj * TS + ty;
        const int mcol0 = ti * TS + txg * 4;
        const int nm    = (p * NROT + mi) * NROT + mcol0;
        const float mri  = (float)(p * NROT + mi);
        const float mrj0 = (float)(p * NROT + mcol0);

        *(float4*)(out + (size_t)0 * nnz + nm) = m0q;
        *(float4*)(out + (size_t)1 * nnz + nm) = m1q;
        *(float4*)(out + (size_t)2 * nnz + nm) = make_float4(fp, fp, fp, fp);
        *(float4*)(out + (size_t)3 * nnz + nm) = make_float4(mri, mri, mri, mri);
        *(float4*)(out + (size_t)4 * nnz + nm) = make_float4(mrj0, mrj0 + 1.0f, mrj0 + 2.0f, mrj0 + 3.0f);
    }
}

extern "C" void kernel_launch(void* const* d_in, const int* in_sizes, int n_in,
                              void* d_out, int out_size, void* d_ws, size_t ws_size,
                              hipStream_t stream) {
    (void)in_sizes; (void)n_in; (void)d_ws; (void)ws_size; (void)out_size;
    const float* coords = (const float*)d_in[0];
    float* out = (float*)d_out;

    dim3 grid(NPOSE * NPAIR);   // 2304 one-wave blocks
    dim3 block(64);
    rot_score_kernel<<<grid, block, 0, stream>>>(coords, out);
}

// Round 6
// 19.062 us; speedup vs baseline: 1.2628x; 1.2628x over previous
//
#include <hip/hip_runtime.h>

typedef float v2f __attribute__((ext_vector_type(2)));

// Structural constants (mirror reference)
#define NPOSE 64
#define NROT  128
#define NATOM 8
#define EPS   1e-2f

#define TS    16                 // rotamer tile size
#define NTILE (NROT / TS)        // 8 tiles per axis
#define NPAIR (NTILE * (NTILE + 1) / 2)   // 36 tile pairs (ti <= tj)
#define CSTR  28                 // coord LDS row stride: 24 + 4 pad, 16B-aligned rows
#define SSTR  17                 // result tile row stride (16 + 1 pad)

__global__ __launch_bounds__(256, 4) void rot_score_kernel(
    const float* __restrict__ coords,
    float* __restrict__ out)
{
    __shared__ float ldsI[TS * CSTR];
    __shared__ float ldsJ[TS * CSTR];
    __shared__ float res0[TS * SSTR];
    __shared__ float res1[TS * SSTR];

    const int bid = blockIdx.x;
    const int p   = bid / NPAIR;
    int t = bid - p * NPAIR;
    int ti = 0;
    while (t >= NTILE - ti) { t -= NTILE - ti; ++ti; }   // unrank upper triangle
    const int tj = ti + t;

    const int tid = threadIdx.x;
    const float* src = coords + (size_t)p * (NROT * NATOM * 3);

    // Stage the two 16-rotamer coordinate sets (16 x 24 floats each), coalesced reads.
    for (int idx = tid; idx < 2 * TS * 24; idx += 256) {
        const int set = idx >= TS * 24;
        const int loc = idx - set * (TS * 24);
        const int r   = loc / 24;
        const int k   = loc - r * 24;
        const float v = src[(set ? tj : ti) * (TS * 24) + loc];
        (set ? ldsJ : ldsI)[r * CSTR + k] = v;
    }
    __syncthreads();

    const int ty = tid >> 4;    // i within tile (0..15)
    const int tx = tid & 15;    // j within tile (0..15)

    // Vector LDS reads: 6x ds_read_b128 per rotamer (rows are 16B-aligned).
    float4 xi4[6], xj4[6];
    {
        const float4* rowI = (const float4*)&ldsI[ty * CSTR];
        const float4* rowJ = (const float4*)&ldsJ[tx * CSTR];
#pragma unroll
        for (int k = 0; k < 6; ++k) { xi4[k] = rowI[k]; xj4[k] = rowJ[k]; }
    }
    float* xi = (float*)xi4;
    const float* xj = (const float*)xj4;

    // Per-atom squared norms; pre-scale xi by -2 so d2 = (sqi+sqj) + sum(xi2*xj).
    float sqi[NATOM];
#pragma unroll
    for (int a = 0; a < NATOM; ++a)
        sqi[a] = fmaf(xi[a*3+2], xi[a*3+2], fmaf(xi[a*3+1], xi[a*3+1], xi[a*3+0]*xi[a*3+0]));
#pragma unroll
    for (int k = 0; k < 24; ++k) xi[k] = xi[k] * -2.0f;

    const float SCH_S = -12102203.0f;   // -(2^23)/ln2  (Schraudolph exp)
    const float SCH_B = 1064866805.0f;  // bias
    const v2f veps = { EPS, EPS };

    v2f s0v = { 0.0f, 0.0f }, s1v = { 0.0f, 0.0f };

#pragma unroll
    for (int bp = 0; bp < 4; ++bp) {
        // pack j-atoms (2bp, 2bp+1)
        const v2f ax = { xj[bp*6 + 0], xj[bp*6 + 3] };
        const v2f ay = { xj[bp*6 + 1], xj[bp*6 + 4] };
        const v2f az = { xj[bp*6 + 2], xj[bp*6 + 5] };
        const v2f sj = __builtin_elementwise_fma(az, az,
                        __builtin_elementwise_fma(ay, ay, ax * ax));
#pragma unroll
        for (int a = 0; a < NATOM; ++a) {
            v2f t = sj + sqi[a];                                    // pk_add (splat)
            t = __builtin_elementwise_fma((v2f)(xi[a*3+0]), ax, t);
            t = __builtin_elementwise_fma((v2f)(xi[a*3+1]), ay, t);
            t = __builtin_elementwise_fma((v2f)(xi[a*3+2]), az, t); // t = d2 pair
            t = __builtin_elementwise_max(t, veps);
            const v2f rs = { __builtin_amdgcn_rsqf(t.x),
                             __builtin_amdgcn_rsqf(t.y) };
            s0v = __builtin_elementwise_fma(rs, rs, s0v);           // += 1/d2
            const v2f dv = t * rs;                                  // sqrt(d2)
            const v2f st = __builtin_elementwise_fma(dv, (v2f)(SCH_S), (v2f)(SCH_B));
            v2f e;
            e.x = __int_as_float((int)st.x);                        // ~ exp(-d)
            e.y = __int_as_float((int)st.y);
            s1v += e;
        }
    }
    const float s0 = s0v.x + s0v.y;
    const float s1 = s1v.x + s1v.y;

    // Stage results for the coalesced mirror write.
    res0[ty * SSTR + tx] = s0;
    res1[ty * SSTR + tx] = s1;

    const int nnz = NPOSE * NROT * NROT;
    const int gi  = ti * TS + ty;
    const int gj  = tj * TS + tx;
    const int n   = (p * NROT + gi) * NROT + gj;

    out[0 * nnz + n] = s0;
    out[1 * nnz + n] = s1;
    out[2 * nnz + n] = (float)p;
    out[3 * nnz + n] = (float)(p * NROT + gi);
    out[4 * nnz + n] = (float)(p * NROT + gj);

    if (ti != tj) {              // block-uniform branch
        __syncthreads();
        const float m0 = res0[tx * SSTR + ty];   // value of pair (ti*TS+tx, tj*TS+ty)
        const float m1 = res1[tx * SSTR + ty];
        const int mi = tj * TS + ty;
        const int mj = ti * TS + tx;
        const int nm = (p * NROT + mi) * NROT + mj;
        out[0 * nnz + nm] = m0;
        out[1 * nnz + nm] = m1;
        out[2 * nnz + nm] = (float)p;
        out[3 * nnz + nm] = (float)(p * NROT + mi);
        out[4 * nnz + nm] = (float)(p * NROT + mj);
    }
}

extern "C" void kernel_launch(void* const* d_in, const int* in_sizes, int n_in,
                              void* d_out, int out_size, void* d_ws, size_t ws_size,
                              hipStream_t stream) {
    (void)in_sizes; (void)n_in; (void)d_ws; (void)ws_size; (void)out_size;
    const float* coords = (const float*)d_in[0];
    float* out = (float*)d_out;

    dim3 grid(NPOSE * NPAIR);   // 64 poses x 36 upper-triangle tile pairs = 2304 blocks
    dim3 block(256);
    rot_score_kernel<<<grid, block, 0, stream>>>(coords, out);
}